// Round 3
// baseline (672.016 us; speedup 1.0000x reference)
//
#include <hip/hip_runtime.h>

// PerformerAttention on MI355X (gfx950). I/O is FLOAT32 (per reference dtypes);
// internal compute uses bf16 MFMA with f32 accumulation.
// Pipeline: transpose+bf16-cast weights -> QKV proj f32->bf16 (+hk, k_stab) ->
// fused per-chunk phi-feature recompute -> chunk k'v sums -> in-place chunk prefix
// -> chunk output (scores/num/den) -> out proj (f32 out). CTX aliases QS.
// Workspace need: 95,420,416 B. Guard kernel floods output with 10000+ws_MB if short.

typedef unsigned short u16;
typedef unsigned int u32;
typedef __attribute__((ext_vector_type(8))) short bf16x8;
typedef __attribute__((ext_vector_type(4))) float f32x4;

#define MFMA(a, b, c) __builtin_amdgcn_mfma_f32_16x16x32_bf16(a, b, c, 0, 0, 0)
#define WS_NEED 95420416ull

__device__ __forceinline__ float bf2f(u16 u) { return __uint_as_float(((u32)u) << 16); }
__device__ __forceinline__ u16 f2bf(float f) {
  u32 i = __float_as_uint(f);
  u32 r = i + 0x7FFFu + ((i >> 16) & 1u);
  return (u16)(r >> 16);
}
// monotonic f32 -> u32 key (atomicMax on floats incl. negatives)
__device__ __forceinline__ u32 fkey(float x) {
  u32 b = __float_as_uint(x);
  return (b & 0x80000000u) ? ~b : (b | 0x80000000u);
}
__device__ __forceinline__ float unfkey(u32 k) {
  return (k & 0x80000000u) ? __uint_as_float(k & 0x7FFFFFFFu) : __uint_as_float(~k);
}
__device__ __forceinline__ uint4 pack_u16x8(const u16 s[8]) {
  uint4 q;
  q.x = (u32)s[0] | ((u32)s[1] << 16);
  q.y = (u32)s[2] | ((u32)s[3] << 16);
  q.z = (u32)s[4] | ((u32)s[5] << 16);
  q.w = (u32)s[6] | ((u32)s[7] << 16);
  return q;
}

// ---------------- transpose + f32->bf16 cast: dst[c][r] = bf16(src[r][c]) ----------------
__global__ __launch_bounds__(256) void k_transpose(const float* __restrict__ src,
                                                   u16* __restrict__ dst, int R, int C) {
  __shared__ u16 t[64 * 65];
  int r0 = blockIdx.y * 64, c0 = blockIdx.x * 64;
  for (int i = threadIdx.x; i < 4096; i += 256) {
    int rr = i >> 6, cc = i & 63;
    t[rr * 65 + cc] = f2bf(src[(size_t)(r0 + rr) * C + c0 + cc]);
  }
  __syncthreads();
  for (int i = threadIdx.x; i < 4096; i += 256) {
    int cc = i >> 6, rr = i & 63;
    dst[(size_t)(c0 + cc) * R + r0 + rr] = t[rr * 65 + cc];
  }
}

__global__ void k_init(u32* kstab) { *kstab = fkey(-1e30f); }

// guard: if workspace too small, flood output with a diagnostic marker (runs LAST)
__global__ __launch_bounds__(256) void k_guard(float* __restrict__ out, size_t ws_size, int n) {
  if (ws_size >= WS_NEED) return;
  int idx = blockIdx.x * 256 + threadIdx.x;
  if (idx < n) out[idx] = 10000.0f + (float)(ws_size >> 20);
}

// ---------------- projection GEMM ----------------
// C[128 x 64] tile of X[8192,1024] @ W[1024,1024] (+bias). WT is bf16 W^T [n][k].
// mode 0: Q(f32) -> QS bf16 [b][h][l][d] scaled; 1: K -> KS + hk + kstab; 2: V -> VH;
// mode 3: CTX(bf16, QS-layout [b][h][l][d]) @ Wo -> d_out f32 [b*l][1024].
__global__ __launch_bounds__(256) void k_proj(const void* __restrict__ X,
                                              const u16* __restrict__ WT,
                                              const float* __restrict__ bias,
                                              void* __restrict__ dst, float* __restrict__ HK,
                                              u32* __restrict__ kstab, int mode) {
  __shared__ __align__(16) u16 Xs[128 * 72];
  __shared__ __align__(16) u16 Ws[64 * 72];
  const int tid = threadIdx.x;
  const int w = tid >> 6, lane = tid & 63, quad = lane >> 4, l15 = lane & 15;
  const int row0 = blockIdx.y * 128;
  const int n0 = blockIdx.x * 64;
  f32x4 acc[2][4] = {};
  for (int kb = 0; kb < 1024; kb += 64) {
    if (mode <= 2) {
      const float* Xf = (const float*)X;
#pragma unroll
      for (int i = 0; i < 8; ++i) {
        int v = tid + i * 256;
        int rr = v >> 4, c4 = (v & 15) << 2;
        float4 t = *(const float4*)&Xf[(size_t)(row0 + rr) * 1024 + kb + c4];
        u32 lo = (u32)f2bf(t.x) | ((u32)f2bf(t.y) << 16);
        u32 hi = (u32)f2bf(t.z) | ((u32)f2bf(t.w) << 16);
        *(uint2*)&Xs[rr * 72 + c4] = make_uint2(lo, hi);
      }
    } else {
      const u16* Xb = (const u16*)X;  // CTX in [b][h][l][d]; K-block kb covers head kb/64
#pragma unroll
      for (int i = 0; i < 4; ++i) {
        int v = tid + i * 256;
        int rr = v >> 3, c8 = (v & 7) << 3;
        int gr = row0 + rr, bb = gr >> 11, ll = gr & 2047;
        *(uint4*)&Xs[rr * 72 + c8] =
            *(const uint4*)&Xb[(((size_t)bb * 16 + (kb >> 6)) * 2048 + ll) * 64 + c8];
      }
    }
#pragma unroll
    for (int i = 0; i < 2; ++i) {
      int v = tid + i * 256;
      int rr = v >> 3, c8 = (v & 7) << 3;
      *(uint4*)&Ws[rr * 72 + c8] = *(const uint4*)&WT[(size_t)(n0 + rr) * 1024 + kb + c8];
    }
    __syncthreads();
#pragma unroll
    for (int kk = 0; kk < 2; ++kk) {
      bf16x8 a[2], bfr[4];
#pragma unroll
      for (int rt = 0; rt < 2; ++rt)
        a[rt] = *(const bf16x8*)&Xs[(w * 32 + rt * 16 + l15) * 72 + kk * 32 + quad * 8];
#pragma unroll
      for (int ct = 0; ct < 4; ++ct)
        bfr[ct] = *(const bf16x8*)&Ws[(ct * 16 + l15) * 72 + kk * 32 + quad * 8];
#pragma unroll
      for (int rt = 0; rt < 2; ++rt)
#pragma unroll
        for (int ct = 0; ct < 4; ++ct) acc[rt][ct] = MFMA(a[rt], bfr[ct], acc[rt][ct]);
    }
    __syncthreads();
  }
  const float sinv = 0.17677669529663687f;  // 1/1024^0.25
  float sq[2][4] = {};
#pragma unroll
  for (int rt = 0; rt < 2; ++rt)
#pragma unroll
    for (int ct = 0; ct < 4; ++ct) {
      int col = ct * 16 + l15;
      float bv = bias[n0 + col];
#pragma unroll
      for (int r = 0; r < 4; ++r) {
        int row = w * 32 + rt * 16 + quad * 4 + r;
        float vv = acc[rt][ct][r] + bv;
        if (mode <= 1) vv *= sinv;
        if (mode == 1) sq[rt][r] += vv * vv;
        int gr = row0 + row;
        if (mode == 3) {
          ((float*)dst)[(size_t)gr * 1024 + n0 + col] = vv;
        } else {
          int bb = gr >> 11, ll = gr & 2047;
          ((u16*)dst)[(((size_t)bb * 16 + blockIdx.x) * 2048 + ll) * 64 + col] = f2bf(vv);
        }
      }
    }
  if (mode == 1) {
    float mx = -3.4e38f;
#pragma unroll
    for (int rt = 0; rt < 2; ++rt)
#pragma unroll
      for (int r = 0; r < 4; ++r) {
        float s = sq[rt][r];
        s += __shfl_xor(s, 1);
        s += __shfl_xor(s, 2);
        s += __shfl_xor(s, 4);
        s += __shfl_xor(s, 8);
        float hkv = -0.5f * s;
        if (l15 == 0) {
          int gr = row0 + w * 32 + rt * 16 + quad * 4 + r;
          int bb = gr >> 11, ll = gr & 2047;
          HK[((size_t)bb * 16 + blockIdx.x) * 2048 + ll] = hkv;
        }
        mx = fmaxf(mx, hkv);
      }
    mx = fmaxf(mx, __shfl_xor(mx, 16));
    mx = fmaxf(mx, __shfl_xor(mx, 32));
    if (lane == 0) atomicMax(kstab, fkey(mx));
  }
}

// ---------------- fused per-chunk S^T = vc^T @ phi_k(kc) and zsum ----------------
// grid.x = bhn (1024). kp recomputed in-kernel from KS + RFt.
// SS bf16 [bhn][64 d][256 m], ZS f32 [bhn][256].
__global__ __launch_bounds__(256) void k_chunksum(const u16* __restrict__ KS,
                                                  const u16* __restrict__ VH,
                                                  const u16* __restrict__ RFt,
                                                  const float* __restrict__ HK,
                                                  const u32* __restrict__ kstab,
                                                  u16* __restrict__ SS,
                                                  float* __restrict__ ZS) {
  // LDS (u16 idx): ks_l @0 (128x72, init only); per-mfb: rf_l @0 (64x72),
  // kpT_l @4608 (64 mf x 136 j); vT @13312 (64 d x 136 j, persistent);
  // hk_l f32[128] @22016; zpart f32[4][64] @22272. total 22784 u16 = 45568 B.
  __shared__ __align__(16) u16 smem[22784];
  float* hk_l = (float*)&smem[22016];
  float* zpart = (float*)&smem[22272];
  const int tid = threadIdx.x;
  const int w = tid >> 6, lane = tid & 63, quad = lane >> 4, l15 = lane & 15;
  const int bhn = blockIdx.x, bh = bhn >> 4, n = bhn & 15;
  const u16* kc = KS + (size_t)bhn * 8192;  // [128][64]
  const u16* vc = VH + (size_t)bhn * 8192;  // [128][64]
  const float kst = unfkey(*kstab);
#pragma unroll
  for (int i = 0; i < 4; ++i) {
    int v = tid + i * 256;
    int rr = v >> 3, c8 = (v & 7) << 3;
    *(uint4*)&smem[rr * 72 + c8] = *(const uint4*)&kc[(size_t)rr * 64 + c8];
  }
  {
    int d = tid & 63, jg = tid >> 6;
#pragma unroll
    for (int g = 0; g < 4; ++g) {
      int j0 = jg * 32 + g * 8;
      u16 s[8];
#pragma unroll
      for (int e = 0; e < 8; ++e) s[e] = vc[(size_t)(j0 + e) * 64 + d];
      *(uint4*)&smem[13312 + d * 136 + j0] = pack_u16x8(s);
    }
  }
  if (tid < 128) hk_l[tid] = HK[(size_t)bh * 2048 + n * 128 + tid];
  __syncthreads();
  bf16x8 ak[2][2];
#pragma unroll
  for (int rt = 0; rt < 2; ++rt)
#pragma unroll
    for (int kk = 0; kk < 2; ++kk)
      ak[rt][kk] = *(const bf16x8*)&smem[(w * 32 + rt * 16 + l15) * 72 + kk * 32 + quad * 8];
  for (int mfb = 0; mfb < 4; ++mfb) {
    __syncthreads();  // prior reads of rf_l/kpT_l (or ks_l) done
#pragma unroll
    for (int i = 0; i < 2; ++i) {
      int v = tid + i * 256;
      int rr = v >> 3, c8 = (v & 7) << 3;
      *(uint4*)&smem[rr * 72 + c8] = *(const uint4*)&RFt[(size_t)(mfb * 64 + rr) * 64 + c8];
    }
    __syncthreads();
    f32x4 fk[2][4] = {};
#pragma unroll
    for (int kk = 0; kk < 2; ++kk) {
      bf16x8 rb[4];
#pragma unroll
      for (int ct = 0; ct < 4; ++ct)
        rb[ct] = *(const bf16x8*)&smem[(ct * 16 + l15) * 72 + kk * 32 + quad * 8];
#pragma unroll
      for (int rt = 0; rt < 2; ++rt)
#pragma unroll
        for (int ct = 0; ct < 4; ++ct) fk[rt][ct] = MFMA(ak[rt][kk], rb[ct], fk[rt][ct]);
    }
    float zp4[4] = {0.f, 0.f, 0.f, 0.f};
#pragma unroll
    for (int rt = 0; rt < 2; ++rt)
#pragma unroll
      for (int ct = 0; ct < 4; ++ct) {
        int ml = ct * 16 + l15;
#pragma unroll
        for (int r = 0; r < 4; ++r) {
          int j = w * 32 + rt * 16 + quad * 4 + r;
          float kv = 0.0625f * (expf(fminf(hk_l[j] + fk[rt][ct][r] - kst, 80.f)) + 1e-4f);
          smem[4608 + ml * 136 + j] = f2bf(kv);
          zp4[ct] += kv;
        }
      }
#pragma unroll
    for (int ct = 0; ct < 4; ++ct) {
      float s = zp4[ct];
      s += __shfl_xor(s, 16);
      s += __shfl_xor(s, 32);
      if (quad == 0) zpart[w * 64 + ct * 16 + l15] = s;
    }
    __syncthreads();
    // Ssum: C[64 d][16 mf per warp] += vT(A) * kpT(B), K=j 128
    f32x4 acc[4] = {};
#pragma unroll
    for (int kk4 = 0; kk4 < 4; ++kk4) {
      bf16x8 bK = *(const bf16x8*)&smem[4608 + (w * 16 + l15) * 136 + kk4 * 32 + quad * 8];
#pragma unroll
      for (int dt = 0; dt < 4; ++dt) {
        bf16x8 aV = *(const bf16x8*)&smem[13312 + (dt * 16 + l15) * 136 + kk4 * 32 + quad * 8];
        acc[dt] = MFMA(aV, bK, acc[dt]);
      }
    }
#pragma unroll
    for (int dt = 0; dt < 4; ++dt)
#pragma unroll
      for (int r = 0; r < 4; ++r) {
        int d = dt * 16 + quad * 4 + r;
        int mf = mfb * 64 + w * 16 + l15;
        SS[((size_t)bhn * 64 + d) * 256 + mf] = f2bf(acc[dt][r]);
      }
    if (tid < 64) {
      float s = zpart[tid] + zpart[64 + tid] + zpart[128 + tid] + zpart[192 + tid];
      ZS[(size_t)bhn * 256 + mfb * 64 + tid] = s;
    }
  }
}

// ---------------- in-place exclusive prefix over chunks ----------------
// grid.x = bh*4 + dg (256 blocks). SSP transformed in place; ZS -> ZP.
__global__ __launch_bounds__(256) void k_prefix(u16* __restrict__ SSP,
                                                const float* __restrict__ ZS,
                                                float* __restrict__ ZP) {
  const int bh = blockIdx.x >> 2, dg = blockIdx.x & 3;
  const int tid = threadIdx.x;
  float run[16];
#pragma unroll
  for (int i = 0; i < 16; ++i) run[i] = 0.f;
  for (int n = 0; n < 16; ++n) {
    size_t cb = ((size_t)bh * 16 + n) * 16384 + dg * 4096 + tid;
#pragma unroll
    for (int i = 0; i < 16; ++i) {
      size_t idx = cb + (size_t)i * 256;
      float s = bf2f(SSP[idx]);  // read BEFORE write (in-place scan)
      SSP[idx] = f2bf(run[i]);
      run[i] += s;
    }
  }
  if (dg == 0) {
    float zr = 0.f;
    for (int n = 0; n < 16; ++n) {
      size_t zi = ((size_t)bh * 16 + n) * 256 + tid;
      float s = ZS[zi];
      ZP[zi] = zr;
      zr += s;
    }
  }
}

// ---------------- fused per-chunk output ----------------
// grid.x = bhn (1024). phi(q),phi(k) recomputed in-kernel from QS/KS + RFt.
// CTX aliases QS ([b][h][l][d]); block bhn writes only the chunk it staged at init.
__global__ __launch_bounds__(256) void k_chunkout(const u16* __restrict__ QS,
                                                  const u16* __restrict__ KS,
                                                  const u16* __restrict__ VH,
                                                  const u16* __restrict__ SP,
                                                  const float* __restrict__ ZP,
                                                  const u16* __restrict__ RFt,
                                                  const float* __restrict__ HK,
                                                  const u32* __restrict__ kstab,
                                                  u16* __restrict__ CTX) {
  // LDS (u16 idx): init: qs_l @0 (128x72), ks_l @9216 (128x72).
  // per-mfb: rf_l @0 (64x72), qp_l @4608 (128x72), kp_l @13824 (128x72), sp_l @23040 (64x72).
  // phase2/3: A_l @0 (128x136), vT @17408 (64x136).
  // persistent: hk_l f32[128] @27648, den_l f32[128] @27904. total 28160 u16 = 56320 B.
  __shared__ __align__(16) u16 smem[28160];
  float* hk_l = (float*)&smem[27648];
  float* den_l = (float*)&smem[27904];
  const int tid = threadIdx.x;
  const int w = tid >> 6, lane = tid & 63, quad = lane >> 4, l15 = lane & 15;
  const int bhn = blockIdx.x, bh = bhn >> 4, n = bhn & 15;
  const u16* qc = QS + (size_t)bhn * 8192;
  const u16* kc = KS + (size_t)bhn * 8192;
  const u16* vc = VH + (size_t)bhn * 8192;
  const u16* sp = SP + (size_t)bhn * 16384;  // [64 d][256 m]
  const float* zp = ZP + (size_t)bhn * 256;
  const float kst = unfkey(*kstab);
#pragma unroll
  for (int i = 0; i < 4; ++i) {
    int v = tid + i * 256;
    int rr = v >> 3, c8 = (v & 7) << 3;
    *(uint4*)&smem[rr * 72 + c8] = *(const uint4*)&qc[(size_t)rr * 64 + c8];
    *(uint4*)&smem[9216 + rr * 72 + c8] = *(const uint4*)&kc[(size_t)rr * 64 + c8];
  }
  if (tid < 128) hk_l[tid] = HK[(size_t)bh * 2048 + n * 128 + tid];
  __syncthreads();
  bf16x8 aq[2][2], ak[2][2];
#pragma unroll
  for (int rt = 0; rt < 2; ++rt)
#pragma unroll
    for (int kk = 0; kk < 2; ++kk) {
      aq[rt][kk] = *(const bf16x8*)&smem[(w * 32 + rt * 16 + l15) * 72 + kk * 32 + quad * 8];
      ak[rt][kk] =
          *(const bf16x8*)&smem[9216 + (w * 32 + rt * 16 + l15) * 72 + kk * 32 + quad * 8];
    }
  f32x4 sc[2][8] = {};
  f32x4 nm[2][4] = {};
  float den2p[2][4] = {};
  for (int mfb = 0; mfb < 4; ++mfb) {
    __syncthreads();  // prior reads of pool done
#pragma unroll
    for (int i = 0; i < 2; ++i) {
      int v = tid + i * 256;
      int rr = v >> 3, c8 = (v & 7) << 3;
      *(uint4*)&smem[rr * 72 + c8] = *(const uint4*)&RFt[(size_t)(mfb * 64 + rr) * 64 + c8];
      *(uint4*)&smem[23040 + rr * 72 + c8] = *(const uint4*)&sp[(size_t)rr * 256 + mfb * 64 + c8];
    }
    __syncthreads();
    // feature GEMMs: fq/fk [128 rows][64 mf] in C/D regs
    f32x4 fq[2][4] = {}, fk[2][4] = {};
#pragma unroll
    for (int kk = 0; kk < 2; ++kk) {
      bf16x8 rb[4];
#pragma unroll
      for (int ct = 0; ct < 4; ++ct)
        rb[ct] = *(const bf16x8*)&smem[(ct * 16 + l15) * 72 + kk * 32 + quad * 8];
#pragma unroll
      for (int rt = 0; rt < 2; ++rt)
#pragma unroll
        for (int ct = 0; ct < 4; ++ct) {
          fq[rt][ct] = MFMA(aq[rt][kk], rb[ct], fq[rt][ct]);
          fk[rt][ct] = MFMA(ak[rt][kk], rb[ct], fk[rt][ct]);
        }
    }
#pragma unroll
    for (int ct = 0; ct < 4; ++ct) {
      int ml = ct * 16 + l15;
      float zpv = zp[mfb * 64 + ml];
#pragma unroll
      for (int rt = 0; rt < 2; ++rt)
#pragma unroll
        for (int r = 0; r < 4; ++r) {
          int row = w * 32 + rt * 16 + quad * 4 + r;
          float qv = 0.0625f * (expf(fminf(fq[rt][ct][r], 80.f)) + 1e-4f);
          smem[4608 + row * 72 + ml] = f2bf(qv);
          den2p[rt][r] += qv * zpv;
          float kv = 0.0625f * (expf(fminf(hk_l[row] + fk[rt][ct][r] - kst, 80.f)) + 1e-4f);
          smem[13824 + row * 72 + ml] = f2bf(kv);
        }
    }
    __syncthreads();
    // scores (sc += qp x kp^T) and num-prefix (nm += qp x Sprev^T), K = 64 m
#pragma unroll
    for (int kk = 0; kk < 2; ++kk) {
      bf16x8 aqp[2];
#pragma unroll
      for (int rt = 0; rt < 2; ++rt)
        aqp[rt] =
            *(const bf16x8*)&smem[4608 + (w * 32 + rt * 16 + l15) * 72 + kk * 32 + quad * 8];
      bf16x8 bk8[8];
#pragma unroll
      for (int ct = 0; ct < 8; ++ct)
        bk8[ct] = *(const bf16x8*)&smem[13824 + (ct * 16 + l15) * 72 + kk * 32 + quad * 8];
      bf16x8 bs4[4];
#pragma unroll
      for (int c4 = 0; c4 < 4; ++c4)
        bs4[c4] = *(const bf16x8*)&smem[23040 + (c4 * 16 + l15) * 72 + kk * 32 + quad * 8];
#pragma unroll
      for (int rt = 0; rt < 2; ++rt) {
#pragma unroll
        for (int ct = 0; ct < 8; ++ct) sc[rt][ct] = MFMA(aqp[rt], bk8[ct], sc[rt][ct]);
#pragma unroll
        for (int c4 = 0; c4 < 4; ++c4) nm[rt][c4] = MFMA(aqp[rt], bs4[c4], nm[rt][c4]);
      }
    }
  }
  __syncthreads();  // pool reads done; begin phase 2
  // den2 -> den_l, then tril-mask scores into A_l + rowsums added to den_l
#pragma unroll
  for (int rt = 0; rt < 2; ++rt)
#pragma unroll
    for (int r = 0; r < 4; ++r) {
      float s = den2p[rt][r];
      s += __shfl_xor(s, 1);
      s += __shfl_xor(s, 2);
      s += __shfl_xor(s, 4);
      s += __shfl_xor(s, 8);
      if (l15 == 0) den_l[w * 32 + rt * 16 + quad * 4 + r] = s;
    }
  float rs[2][4] = {};
#pragma unroll
  for (int rt = 0; rt < 2; ++rt)
#pragma unroll
    for (int ct = 0; ct < 8; ++ct)
#pragma unroll
      for (int r = 0; r < 4; ++r) {
        int i = w * 32 + rt * 16 + quad * 4 + r;
        int j = ct * 16 + l15;
        float vv = (j <= i) ? sc[rt][ct][r] : 0.f;
        rs[rt][r] += vv;
        smem[i * 136 + j] = f2bf(vv);
      }
#pragma unroll
  for (int rt = 0; rt < 2; ++rt)
#pragma unroll
    for (int r = 0; r < 4; ++r) {
      float s = rs[rt][r];
      s += __shfl_xor(s, 1);
      s += __shfl_xor(s, 2);
      s += __shfl_xor(s, 4);
      s += __shfl_xor(s, 8);
      if (l15 == 0) den_l[w * 32 + rt * 16 + quad * 4 + r] += s;  // same thread as den2 write
    }
  // stage vT [64 d][136 j]
  {
    int d = tid & 63, jg = tid >> 6;
#pragma unroll
    for (int g = 0; g < 4; ++g) {
      int j0 = jg * 32 + g * 8;
      u16 s[8];
#pragma unroll
      for (int e = 0; e < 8; ++e) s[e] = vc[(size_t)(j0 + e) * 64 + d];
      *(uint4*)&smem[17408 + d * 136 + j0] = pack_u16x8(s);
    }
  }
  __syncthreads();
  // num += A @ vc (K = 128 j)
#pragma unroll
  for (int kk4 = 0; kk4 < 4; ++kk4) {
    bf16x8 aA[2];
#pragma unroll
    for (int rt = 0; rt < 2; ++rt)
      aA[rt] = *(const bf16x8*)&smem[(w * 32 + rt * 16 + l15) * 136 + kk4 * 32 + quad * 8];
    bf16x8 bv4[4];
#pragma unroll
    for (int c4 = 0; c4 < 4; ++c4)
      bv4[c4] = *(const bf16x8*)&smem[17408 + (c4 * 16 + l15) * 136 + kk4 * 32 + quad * 8];
#pragma unroll
    for (int rt = 0; rt < 2; ++rt)
#pragma unroll
      for (int c4 = 0; c4 < 4; ++c4) nm[rt][c4] = MFMA(aA[rt], bv4[c4], nm[rt][c4]);
  }
  if (tid < 128) {
    float dv = den_l[tid];
    if (fabsf(dv) <= 1e-6f) dv += 2e-6f;
    den_l[tid] = dv;
  }
  __syncthreads();
  // out = num / den -> CTX (QS alias, [b][h][l][d]): exactly the chunk this block staged
#pragma unroll
  for (int rt = 0; rt < 2; ++rt)
#pragma unroll
    for (int c4 = 0; c4 < 4; ++c4)
#pragma unroll
      for (int r = 0; r < 4; ++r) {
        int i = w * 32 + rt * 16 + quad * 4 + r;
        int d = c4 * 16 + l15;
        float o = nm[rt][c4][r] / den_l[i];
        CTX[(size_t)bhn * 8192 + (size_t)i * 64 + d] = f2bf(o);
      }
}

extern "C" void kernel_launch(void* const* d_in, const int* in_sizes, int n_in,
                              void* d_out, int out_size, void* d_ws, size_t ws_size,
                              hipStream_t stream) {
  const float* q = (const float*)d_in[0];
  const float* k = (const float*)d_in[1];
  const float* v = (const float*)d_in[2];
  const float* Wq = (const float*)d_in[3];
  const float* bq = (const float*)d_in[4];
  const float* Wk = (const float*)d_in[5];
  const float* bk = (const float*)d_in[6];
  const float* Wv = (const float*)d_in[7];
  const float* bv = (const float*)d_in[8];
  const float* Wo = (const float*)d_in[9];
  const float* bo = (const float*)d_in[10];
  const float* RF = (const float*)d_in[11];
  char* W = (char*)d_ws;
  // workspace layout (bytes); total need 95,420,416 (~91 MB)
  u16* WqT = (u16*)(W + 0);
  u16* WkT = (u16*)(W + 2097152);
  u16* WvT = (u16*)(W + 4194304);
  u16* WoT = (u16*)(W + 6291456);
  u16* RFt = (u16*)(W + 8388608);
  u32* KSTAB = (u32*)(W + 8421376);
  float* HK = (float*)(W + 8421632);
  float* ZS = (float*)(W + 8945920);
  float* ZP = (float*)(W + 9994496);
  u16* QS = (u16*)(W + 11534336);
  u16* KS = (u16*)(W + 28311552);
  u16* VH = (u16*)(W + 45088768);
  u16* SS = (u16*)(W + 61865984);  // becomes Sprev in place after k_prefix; ends 95,420,416
  u16* CTX = QS;                   // alias: k_chunkout writes exactly the chunk it consumed

  k_transpose<<<dim3(16, 16), 256, 0, stream>>>(Wq, WqT, 1024, 1024);
  k_transpose<<<dim3(16, 16), 256, 0, stream>>>(Wk, WkT, 1024, 1024);
  k_transpose<<<dim3(16, 16), 256, 0, stream>>>(Wv, WvT, 1024, 1024);
  k_transpose<<<dim3(16, 16), 256, 0, stream>>>(Wo, WoT, 1024, 1024);
  k_transpose<<<dim3(4, 1), 256, 0, stream>>>(RF, RFt, 64, 256);
  k_init<<<1, 1, 0, stream>>>(KSTAB);
  k_proj<<<dim3(16, 64), 256, 0, stream>>>(q, WqT, bq, QS, HK, KSTAB, 0);
  k_proj<<<dim3(16, 64), 256, 0, stream>>>(k, WkT, bk, KS, HK, KSTAB, 1);
  k_proj<<<dim3(16, 64), 256, 0, stream>>>(v, WvT, bv, VH, HK, KSTAB, 2);
  k_chunksum<<<1024, 256, 0, stream>>>(KS, VH, RFt, HK, KSTAB, SS, ZS);
  k_prefix<<<256, 256, 0, stream>>>(SS, ZS, ZP);
  k_chunkout<<<1024, 256, 0, stream>>>(QS, KS, VH, SS, ZP, RFt, HK, KSTAB, CTX);
  k_proj<<<dim3(16, 64), 256, 0, stream>>>(CTX, WoT, bo, d_out, HK, KSTAB, 3);
  k_guard<<<32768, 256, 0, stream>>>((float*)d_out, ws_size, out_size);
  (void)in_sizes; (void)n_in;
}

// Round 4
// 489.479 us; speedup vs baseline: 1.3729x; 1.3729x over previous
//
#include <hip/hip_runtime.h>

// PerformerAttention on MI355X (gfx950). I/O float32; internal bf16 MFMA, f32 accum.
// R4: k_proj rewritten m97-style: 128x128 tile, global_load_lds(16B) staging for A+B,
// XOR-swizzled LDS (conflict-free ds_read_b128), bf16 pre-cast of q/k/v (k_cast).
// Workspace need unchanged: 95,420,416 B (XB aliases SS; CTX aliases QS).

typedef unsigned short u16;
typedef unsigned int u32;
typedef __attribute__((ext_vector_type(8))) short bf16x8;
typedef __attribute__((ext_vector_type(4))) float f32x4;

#define MFMA(a, b, c) __builtin_amdgcn_mfma_f32_16x16x32_bf16(a, b, c, 0, 0, 0)
#define WS_NEED 95420416ull

__device__ __forceinline__ float bf2f(u16 u) { return __uint_as_float(((u32)u) << 16); }
__device__ __forceinline__ u16 f2bf(float f) {
  u32 i = __float_as_uint(f);
  u32 r = i + 0x7FFFu + ((i >> 16) & 1u);
  return (u16)(r >> 16);
}
__device__ __forceinline__ u32 fkey(float x) {
  u32 b = __float_as_uint(x);
  return (b & 0x80000000u) ? ~b : (b | 0x80000000u);
}
__device__ __forceinline__ float unfkey(u32 k) {
  return (k & 0x80000000u) ? __uint_as_float(k & 0x7FFFFFFFu) : __uint_as_float(~k);
}
__device__ __forceinline__ uint4 pack_u16x8(const u16 s[8]) {
  uint4 q;
  q.x = (u32)s[0] | ((u32)s[1] << 16);
  q.y = (u32)s[2] | ((u32)s[3] << 16);
  q.z = (u32)s[4] | ((u32)s[5] << 16);
  q.w = (u32)s[6] | ((u32)s[7] << 16);
  return q;
}
// async global->LDS DMA, 16B/lane; LDS dest is wave-uniform base (HW adds lane*16)
__device__ __forceinline__ void gl_lds16(const u16* g, u16* l) {
  __builtin_amdgcn_global_load_lds((const __attribute__((address_space(1))) unsigned int*)g,
                                   (__attribute__((address_space(3))) unsigned int*)l, 16, 0, 0);
}

// ---------------- f32 -> bf16 cast, 8 elems/thread ----------------
__global__ __launch_bounds__(256) void k_cast(const float* __restrict__ src,
                                              u16* __restrict__ dst, int n8) {
  int idx = blockIdx.x * 256 + threadIdx.x;
  if (idx >= n8) return;
  const float4* s = (const float4*)src;
  float4 t0 = s[(size_t)idx * 2], t1 = s[(size_t)idx * 2 + 1];
  u16 p[8] = {f2bf(t0.x), f2bf(t0.y), f2bf(t0.z), f2bf(t0.w),
              f2bf(t1.x), f2bf(t1.y), f2bf(t1.z), f2bf(t1.w)};
  *(uint4*)&dst[(size_t)idx * 8] = pack_u16x8(p);
}

// ---------------- transpose + f32->bf16 cast: dst[c][r] = bf16(src[r][c]) ----------------
__global__ __launch_bounds__(256) void k_transpose(const float* __restrict__ src,
                                                   u16* __restrict__ dst, int R, int C) {
  __shared__ u16 t[64 * 65];
  int r0 = blockIdx.y * 64, c0 = blockIdx.x * 64;
  for (int i = threadIdx.x; i < 4096; i += 256) {
    int rr = i >> 6, cc = i & 63;
    t[rr * 65 + cc] = f2bf(src[(size_t)(r0 + rr) * C + c0 + cc]);
  }
  __syncthreads();
  for (int i = threadIdx.x; i < 4096; i += 256) {
    int cc = i >> 6, rr = i & 63;
    dst[(size_t)(c0 + cc) * R + r0 + rr] = t[rr * 65 + cc];
  }
}

__global__ void k_init(u32* kstab) { *kstab = fkey(-1e30f); }

__global__ __launch_bounds__(256) void k_guard(float* __restrict__ out, size_t ws_size, int n) {
  if (ws_size >= WS_NEED) return;
  int idx = blockIdx.x * 256 + threadIdx.x;
  if (idx < n) out[idx] = 10000.0f + (float)(ws_size >> 20);
}

// ---------------- projection GEMM (m97 structure) ----------------
// C[128 x 128] tile, 4 waves 2x2, BK=64, global_load_lds staging, XOR-swizzled LDS.
// modes 0/1/2: XB bf16 [8192][1024] @ WT -> QS/KS/VH bf16 [b][h][l][d] (x1/scale);
//   mode 1 also hk + kstab. mode 3: CTX bf16 [b][h][l][d] @ WoT -> d_out f32.
__global__ __launch_bounds__(256) void k_proj(const void* __restrict__ X,
                                              const u16* __restrict__ WT,
                                              const float* __restrict__ bias,
                                              void* __restrict__ dst, float* __restrict__ HK,
                                              u32* __restrict__ kstab, int mode) {
  __shared__ __align__(16) u16 As[128 * 64];
  __shared__ __align__(16) u16 Bs[128 * 64];
  const int tid = threadIdx.x;
  const int w = tid >> 6, lane = tid & 63, quad = lane >> 4, l15 = lane & 15;
  const int wr = w >> 1, wc = w & 1;
  const int row0 = blockIdx.y * 128;
  const int n0 = blockIdx.x * 128;
  const int lr = lane >> 3;               // row-within-8 for DMA
  const int sub = lane & 7;               // 16B chunk within row
  const int colo = ((sub ^ lr) << 3);     // swizzled element offset (8 elems = 16B)
  const u16* Xb = (const u16*)X;
  const int bb3 = row0 >> 11, l03 = row0 & 2047;  // mode-3 helpers (block spans one b)
  f32x4 acc[4][4] = {};
  for (int kb = 0; kb < 1024; kb += 64) {
    __syncthreads();  // fragment reads of previous iter complete
#pragma unroll
    for (int i = 0; i < 4; ++i)
      gl_lds16(&WT[(size_t)(n0 + w * 32 + i * 8 + lr) * 1024 + kb + colo],
               &Bs[(w * 4 + i) * 512]);
    if (mode <= 2) {
#pragma unroll
      for (int i = 0; i < 4; ++i)
        gl_lds16(&Xb[(size_t)(row0 + w * 32 + i * 8 + lr) * 1024 + kb + colo],
                 &As[(w * 4 + i) * 512]);
    } else {
      const int hh = kb >> 6;
#pragma unroll
      for (int i = 0; i < 4; ++i)
        gl_lds16(&Xb[(((size_t)bb3 * 16 + hh) * 2048 + l03 + w * 32 + i * 8 + lr) * 64 + colo],
                 &As[(w * 4 + i) * 512]);
    }
    __syncthreads();  // vmcnt(0) drain: DMA writes visible
#pragma unroll
    for (int kk = 0; kk < 2; ++kk) {
      const int s2 = ((kk * 4 + quad) ^ (l15 & 7)) << 3;
      bf16x8 a[4], b[4];
#pragma unroll
      for (int rt = 0; rt < 4; ++rt)
        a[rt] = *(const bf16x8*)&As[(wr * 64 + rt * 16 + l15) * 64 + s2];
#pragma unroll
      for (int ct = 0; ct < 4; ++ct)
        b[ct] = *(const bf16x8*)&Bs[(wc * 64 + ct * 16 + l15) * 64 + s2];
#pragma unroll
      for (int rt = 0; rt < 4; ++rt)
#pragma unroll
        for (int ct = 0; ct < 4; ++ct) acc[rt][ct] = MFMA(a[rt], b[ct], acc[rt][ct]);
    }
  }
  const float sinv = 0.17677669529663687f;  // 1/1024^0.25
  const int h = blockIdx.x * 2 + wc;        // head covered by this wave's 64-col half
  float sq[4][4] = {};
#pragma unroll
  for (int rt = 0; rt < 4; ++rt)
#pragma unroll
    for (int ct = 0; ct < 4; ++ct) {
      int col = wc * 64 + ct * 16 + l15;
      float bv = bias[n0 + col];
#pragma unroll
      for (int r = 0; r < 4; ++r) {
        int gr = row0 + wr * 64 + rt * 16 + quad * 4 + r;
        float vv = acc[rt][ct][r] + bv;
        if (mode <= 1) vv *= sinv;
        if (mode == 1) sq[rt][r] += vv * vv;
        if (mode == 3) {
          ((float*)dst)[(size_t)gr * 1024 + n0 + col] = vv;
        } else {
          int bb = gr >> 11, ll = gr & 2047;
          ((u16*)dst)[(((size_t)bb * 16 + h) * 2048 + ll) * 64 + ct * 16 + l15] = f2bf(vv);
        }
      }
    }
  if (mode == 1) {
    float mx = -3.4e38f;
#pragma unroll
    for (int rt = 0; rt < 4; ++rt)
#pragma unroll
      for (int r = 0; r < 4; ++r) {
        float s = sq[rt][r];
        s += __shfl_xor(s, 1);
        s += __shfl_xor(s, 2);
        s += __shfl_xor(s, 4);
        s += __shfl_xor(s, 8);
        float hkv = -0.5f * s;
        if (l15 == 0) {
          int gr = row0 + wr * 64 + rt * 16 + quad * 4 + r;
          int bb = gr >> 11, ll = gr & 2047;
          HK[((size_t)bb * 16 + h) * 2048 + ll] = hkv;
        }
        mx = fmaxf(mx, hkv);
      }
    mx = fmaxf(mx, __shfl_xor(mx, 16));
    mx = fmaxf(mx, __shfl_xor(mx, 32));
    if (lane == 0) atomicMax(kstab, fkey(mx));
  }
}

// ---------------- fused per-chunk S^T = vc^T @ phi_k(kc) and zsum ----------------
__global__ __launch_bounds__(256) void k_chunksum(const u16* __restrict__ KS,
                                                  const u16* __restrict__ VH,
                                                  const u16* __restrict__ RFt,
                                                  const float* __restrict__ HK,
                                                  const u32* __restrict__ kstab,
                                                  u16* __restrict__ SS,
                                                  float* __restrict__ ZS) {
  __shared__ __align__(16) u16 smem[22784];
  float* hk_l = (float*)&smem[22016];
  float* zpart = (float*)&smem[22272];
  const int tid = threadIdx.x;
  const int w = tid >> 6, lane = tid & 63, quad = lane >> 4, l15 = lane & 15;
  const int bhn = blockIdx.x, bh = bhn >> 4, n = bhn & 15;
  const u16* kc = KS + (size_t)bhn * 8192;
  const u16* vc = VH + (size_t)bhn * 8192;
  const float kst = unfkey(*kstab);
#pragma unroll
  for (int i = 0; i < 4; ++i) {
    int v = tid + i * 256;
    int rr = v >> 3, c8 = (v & 7) << 3;
    *(uint4*)&smem[rr * 72 + c8] = *(const uint4*)&kc[(size_t)rr * 64 + c8];
  }
  {
    int d = tid & 63, jg = tid >> 6;
#pragma unroll
    for (int g = 0; g < 4; ++g) {
      int j0 = jg * 32 + g * 8;
      u16 s[8];
#pragma unroll
      for (int e = 0; e < 8; ++e) s[e] = vc[(size_t)(j0 + e) * 64 + d];
      *(uint4*)&smem[13312 + d * 136 + j0] = pack_u16x8(s);
    }
  }
  if (tid < 128) hk_l[tid] = HK[(size_t)bh * 2048 + n * 128 + tid];
  __syncthreads();
  bf16x8 ak[2][2];
#pragma unroll
  for (int rt = 0; rt < 2; ++rt)
#pragma unroll
    for (int kk = 0; kk < 2; ++kk)
      ak[rt][kk] = *(const bf16x8*)&smem[(w * 32 + rt * 16 + l15) * 72 + kk * 32 + quad * 8];
  for (int mfb = 0; mfb < 4; ++mfb) {
    __syncthreads();
#pragma unroll
    for (int i = 0; i < 2; ++i) {
      int v = tid + i * 256;
      int rr = v >> 3, c8 = (v & 7) << 3;
      *(uint4*)&smem[rr * 72 + c8] = *(const uint4*)&RFt[(size_t)(mfb * 64 + rr) * 64 + c8];
    }
    __syncthreads();
    f32x4 fk[2][4] = {};
#pragma unroll
    for (int kk = 0; kk < 2; ++kk) {
      bf16x8 rb[4];
#pragma unroll
      for (int ct = 0; ct < 4; ++ct)
        rb[ct] = *(const bf16x8*)&smem[(ct * 16 + l15) * 72 + kk * 32 + quad * 8];
#pragma unroll
      for (int rt = 0; rt < 2; ++rt)
#pragma unroll
        for (int ct = 0; ct < 4; ++ct) fk[rt][ct] = MFMA(ak[rt][kk], rb[ct], fk[rt][ct]);
    }
    float zp4[4] = {0.f, 0.f, 0.f, 0.f};
#pragma unroll
    for (int rt = 0; rt < 2; ++rt)
#pragma unroll
      for (int ct = 0; ct < 4; ++ct) {
        int ml = ct * 16 + l15;
#pragma unroll
        for (int r = 0; r < 4; ++r) {
          int j = w * 32 + rt * 16 + quad * 4 + r;
          float kv = 0.0625f * (expf(fminf(hk_l[j] + fk[rt][ct][r] - kst, 80.f)) + 1e-4f);
          smem[4608 + ml * 136 + j] = f2bf(kv);
          zp4[ct] += kv;
        }
      }
#pragma unroll
    for (int ct = 0; ct < 4; ++ct) {
      float s = zp4[ct];
      s += __shfl_xor(s, 16);
      s += __shfl_xor(s, 32);
      if (quad == 0) zpart[w * 64 + ct * 16 + l15] = s;
    }
    __syncthreads();
    f32x4 acc[4] = {};
#pragma unroll
    for (int kk4 = 0; kk4 < 4; ++kk4) {
      bf16x8 bK = *(const bf16x8*)&smem[4608 + (w * 16 + l15) * 136 + kk4 * 32 + quad * 8];
#pragma unroll
      for (int dt = 0; dt < 4; ++dt) {
        bf16x8 aV = *(const bf16x8*)&smem[13312 + (dt * 16 + l15) * 136 + kk4 * 32 + quad * 8];
        acc[dt] = MFMA(aV, bK, acc[dt]);
      }
    }
#pragma unroll
    for (int dt = 0; dt < 4; ++dt)
#pragma unroll
      for (int r = 0; r < 4; ++r) {
        int d = dt * 16 + quad * 4 + r;
        int mf = mfb * 64 + w * 16 + l15;
        SS[((size_t)bhn * 64 + d) * 256 + mf] = f2bf(acc[dt][r]);
      }
    if (tid < 64) {
      float s = zpart[tid] + zpart[64 + tid] + zpart[128 + tid] + zpart[192 + tid];
      ZS[(size_t)bhn * 256 + mfb * 64 + tid] = s;
    }
  }
}

// ---------------- in-place exclusive prefix over chunks ----------------
__global__ __launch_bounds__(256) void k_prefix(u16* __restrict__ SSP,
                                                const float* __restrict__ ZS,
                                                float* __restrict__ ZP) {
  const int bh = blockIdx.x >> 2, dg = blockIdx.x & 3;
  const int tid = threadIdx.x;
  float run[16];
#pragma unroll
  for (int i = 0; i < 16; ++i) run[i] = 0.f;
  for (int n = 0; n < 16; ++n) {
    size_t cb = ((size_t)bh * 16 + n) * 16384 + dg * 4096 + tid;
#pragma unroll
    for (int i = 0; i < 16; ++i) {
      size_t idx = cb + (size_t)i * 256;
      float s = bf2f(SSP[idx]);
      SSP[idx] = f2bf(run[i]);
      run[i] += s;
    }
  }
  if (dg == 0) {
    float zr = 0.f;
    for (int n = 0; n < 16; ++n) {
      size_t zi = ((size_t)bh * 16 + n) * 256 + tid;
      float s = ZS[zi];
      ZP[zi] = zr;
      zr += s;
    }
  }
}

// ---------------- fused per-chunk output ----------------
__global__ __launch_bounds__(256) void k_chunkout(const u16* __restrict__ QS,
                                                  const u16* __restrict__ KS,
                                                  const u16* __restrict__ VH,
                                                  const u16* __restrict__ SP,
                                                  const float* __restrict__ ZP,
                                                  const u16* __restrict__ RFt,
                                                  const float* __restrict__ HK,
                                                  const u32* __restrict__ kstab,
                                                  u16* __restrict__ CTX) {
  __shared__ __align__(16) u16 smem[28160];
  float* hk_l = (float*)&smem[27648];
  float* den_l = (float*)&smem[27904];
  const int tid = threadIdx.x;
  const int w = tid >> 6, lane = tid & 63, quad = lane >> 4, l15 = lane & 15;
  const int bhn = blockIdx.x, bh = bhn >> 4, n = bhn & 15;
  const u16* qc = QS + (size_t)bhn * 8192;
  const u16* kc = KS + (size_t)bhn * 8192;
  const u16* vc = VH + (size_t)bhn * 8192;
  const u16* sp = SP + (size_t)bhn * 16384;
  const float* zp = ZP + (size_t)bhn * 256;
  const float kst = unfkey(*kstab);
#pragma unroll
  for (int i = 0; i < 4; ++i) {
    int v = tid + i * 256;
    int rr = v >> 3, c8 = (v & 7) << 3;
    *(uint4*)&smem[rr * 72 + c8] = *(const uint4*)&qc[(size_t)rr * 64 + c8];
    *(uint4*)&smem[9216 + rr * 72 + c8] = *(const uint4*)&kc[(size_t)rr * 64 + c8];
  }
  if (tid < 128) hk_l[tid] = HK[(size_t)bh * 2048 + n * 128 + tid];
  __syncthreads();
  bf16x8 aq[2][2], ak[2][2];
#pragma unroll
  for (int rt = 0; rt < 2; ++rt)
#pragma unroll
    for (int kk = 0; kk < 2; ++kk) {
      aq[rt][kk] = *(const bf16x8*)&smem[(w * 32 + rt * 16 + l15) * 72 + kk * 32 + quad * 8];
      ak[rt][kk] =
          *(const bf16x8*)&smem[9216 + (w * 32 + rt * 16 + l15) * 72 + kk * 32 + quad * 8];
    }
  f32x4 sc[2][8] = {};
  f32x4 nm[2][4] = {};
  float den2p[2][4] = {};
  for (int mfb = 0; mfb < 4; ++mfb) {
    __syncthreads();
#pragma unroll
    for (int i = 0; i < 2; ++i) {
      int v = tid + i * 256;
      int rr = v >> 3, c8 = (v & 7) << 3;
      *(uint4*)&smem[rr * 72 + c8] = *(const uint4*)&RFt[(size_t)(mfb * 64 + rr) * 64 + c8];
      *(uint4*)&smem[23040 + rr * 72 + c8] = *(const uint4*)&sp[(size_t)rr * 256 + mfb * 64 + c8];
    }
    __syncthreads();
    f32x4 fq[2][4] = {}, fk[2][4] = {};
#pragma unroll
    for (int kk = 0; kk < 2; ++kk) {
      bf16x8 rb[4];
#pragma unroll
      for (int ct = 0; ct < 4; ++ct)
        rb[ct] = *(const bf16x8*)&smem[(ct * 16 + l15) * 72 + kk * 32 + quad * 8];
#pragma unroll
      for (int rt = 0; rt < 2; ++rt)
#pragma unroll
        for (int ct = 0; ct < 4; ++ct) {
          fq[rt][ct] = MFMA(aq[rt][kk], rb[ct], fq[rt][ct]);
          fk[rt][ct] = MFMA(ak[rt][kk], rb[ct], fk[rt][ct]);
        }
    }
#pragma unroll
    for (int ct = 0; ct < 4; ++ct) {
      int ml = ct * 16 + l15;
      float zpv = zp[mfb * 64 + ml];
#pragma unroll
      for (int rt = 0; rt < 2; ++rt)
#pragma unroll
        for (int r = 0; r < 4; ++r) {
          int row = w * 32 + rt * 16 + quad * 4 + r;
          float qv = 0.0625f * (expf(fminf(fq[rt][ct][r], 80.f)) + 1e-4f);
          smem[4608 + row * 72 + ml] = f2bf(qv);
          den2p[rt][r] += qv * zpv;
          float kv = 0.0625f * (expf(fminf(hk_l[row] + fk[rt][ct][r] - kst, 80.f)) + 1e-4f);
          smem[13824 + row * 72 + ml] = f2bf(kv);
        }
    }
    __syncthreads();
#pragma unroll
    for (int kk = 0; kk < 2; ++kk) {
      bf16x8 aqp[2];
#pragma unroll
      for (int rt = 0; rt < 2; ++rt)
        aqp[rt] =
            *(const bf16x8*)&smem[4608 + (w * 32 + rt * 16 + l15) * 72 + kk * 32 + quad * 8];
      bf16x8 bk8[8];
#pragma unroll
      for (int ct = 0; ct < 8; ++ct)
        bk8[ct] = *(const bf16x8*)&smem[13824 + (ct * 16 + l15) * 72 + kk * 32 + quad * 8];
      bf16x8 bs4[4];
#pragma unroll
      for (int c4 = 0; c4 < 4; ++c4)
        bs4[c4] = *(const bf16x8*)&smem[23040 + (c4 * 16 + l15) * 72 + kk * 32 + quad * 8];
#pragma unroll
      for (int rt = 0; rt < 2; ++rt) {
#pragma unroll
        for (int ct = 0; ct < 8; ++ct) sc[rt][ct] = MFMA(aqp[rt], bk8[ct], sc[rt][ct]);
#pragma unroll
        for (int c4 = 0; c4 < 4; ++c4) nm[rt][c4] = MFMA(aqp[rt], bs4[c4], nm[rt][c4]);
      }
    }
  }
  __syncthreads();
#pragma unroll
  for (int rt = 0; rt < 2; ++rt)
#pragma unroll
    for (int r = 0; r < 4; ++r) {
      float s = den2p[rt][r];
      s += __shfl_xor(s, 1);
      s += __shfl_xor(s, 2);
      s += __shfl_xor(s, 4);
      s += __shfl_xor(s, 8);
      if (l15 == 0) den_l[w * 32 + rt * 16 + quad * 4 + r] = s;
    }
  float rs[2][4] = {};
#pragma unroll
  for (int rt = 0; rt < 2; ++rt)
#pragma unroll
    for (int ct = 0; ct < 8; ++ct)
#pragma unroll
      for (int r = 0; r < 4; ++r) {
        int i = w * 32 + rt * 16 + quad * 4 + r;
        int j = ct * 16 + l15;
        float vv = (j <= i) ? sc[rt][ct][r] : 0.f;
        rs[rt][r] += vv;
        smem[i * 136 + j] = f2bf(vv);
      }
#pragma unroll
  for (int rt = 0; rt < 2; ++rt)
#pragma unroll
    for (int r = 0; r < 4; ++r) {
      float s = rs[rt][r];
      s += __shfl_xor(s, 1);
      s += __shfl_xor(s, 2);
      s += __shfl_xor(s, 4);
      s += __shfl_xor(s, 8);
      if (l15 == 0) den_l[w * 32 + rt * 16 + quad * 4 + r] += s;
    }
  {
    int d = tid & 63, jg = tid >> 6;
#pragma unroll
    for (int g = 0; g < 4; ++g) {
      int j0 = jg * 32 + g * 8;
      u16 s[8];
#pragma unroll
      for (int e = 0; e < 8; ++e) s[e] = vc[(size_t)(j0 + e) * 64 + d];
      *(uint4*)&smem[17408 + d * 136 + j0] = pack_u16x8(s);
    }
  }
  __syncthreads();
#pragma unroll
  for (int kk4 = 0; kk4 < 4; ++kk4) {
    bf16x8 aA[2];
#pragma unroll
    for (int rt = 0; rt < 2; ++rt)
      aA[rt] = *(const bf16x8*)&smem[(w * 32 + rt * 16 + l15) * 136 + kk4 * 32 + quad * 8];
    bf16x8 bv4[4];
#pragma unroll
    for (int c4 = 0; c4 < 4; ++c4)
      bv4[c4] = *(const bf16x8*)&smem[17408 + (c4 * 16 + l15) * 136 + kk4 * 32 + quad * 8];
#pragma unroll
    for (int rt = 0; rt < 2; ++rt)
#pragma unroll
      for (int c4 = 0; c4 < 4; ++c4) nm[rt][c4] = MFMA(aA[rt], bv4[c4], nm[rt][c4]);
  }
  if (tid < 128) {
    float dv = den_l[tid];
    if (fabsf(dv) <= 1e-6f) dv += 2e-6f;
    den_l[tid] = dv;
  }
  __syncthreads();
#pragma unroll
  for (int rt = 0; rt < 2; ++rt)
#pragma unroll
    for (int c4 = 0; c4 < 4; ++c4)
#pragma unroll
      for (int r = 0; r < 4; ++r) {
        int i = w * 32 + rt * 16 + quad * 4 + r;
        int d = c4 * 16 + l15;
        float o = nm[rt][c4][r] / den_l[i];
        CTX[(size_t)bhn * 8192 + (size_t)i * 64 + d] = f2bf(o);
      }
}

extern "C" void kernel_launch(void* const* d_in, const int* in_sizes, int n_in,
                              void* d_out, int out_size, void* d_ws, size_t ws_size,
                              hipStream_t stream) {
  const float* q = (const float*)d_in[0];
  const float* k = (const float*)d_in[1];
  const float* v = (const float*)d_in[2];
  const float* Wq = (const float*)d_in[3];
  const float* bq = (const float*)d_in[4];
  const float* Wk = (const float*)d_in[5];
  const float* bk = (const float*)d_in[6];
  const float* Wv = (const float*)d_in[7];
  const float* bv = (const float*)d_in[8];
  const float* Wo = (const float*)d_in[9];
  const float* bo = (const float*)d_in[10];
  const float* RF = (const float*)d_in[11];
  char* W = (char*)d_ws;
  // workspace layout (bytes); total need 95,420,416
  u16* WqT = (u16*)(W + 0);
  u16* WkT = (u16*)(W + 2097152);
  u16* WvT = (u16*)(W + 4194304);
  u16* WoT = (u16*)(W + 6291456);
  u16* RFt = (u16*)(W + 8388608);
  u32* KSTAB = (u32*)(W + 8421376);
  float* HK = (float*)(W + 8421632);
  float* ZS = (float*)(W + 8945920);
  float* ZP = (float*)(W + 9994496);
  u16* QS = (u16*)(W + 11534336);
  u16* KS = (u16*)(W + 28311552);
  u16* VH = (u16*)(W + 45088768);
  u16* SS = (u16*)(W + 61865984);  // Sprev in place after k_prefix
  u16* XB = SS;                    // bf16 input cast buffer; dead before k_chunksum
  u16* CTX = QS;                   // k_chunkout writes exactly the chunk it consumed

  k_transpose<<<dim3(16, 16), 256, 0, stream>>>(Wq, WqT, 1024, 1024);
  k_transpose<<<dim3(16, 16), 256, 0, stream>>>(Wk, WkT, 1024, 1024);
  k_transpose<<<dim3(16, 16), 256, 0, stream>>>(Wv, WvT, 1024, 1024);
  k_transpose<<<dim3(16, 16), 256, 0, stream>>>(Wo, WoT, 1024, 1024);
  k_transpose<<<dim3(4, 1), 256, 0, stream>>>(RF, RFt, 64, 256);
  k_init<<<1, 1, 0, stream>>>(KSTAB);
  k_cast<<<4096, 256, 0, stream>>>(q, XB, 1048576);
  k_proj<<<dim3(8, 64), 256, 0, stream>>>(XB, WqT, bq, QS, HK, KSTAB, 0);
  k_cast<<<4096, 256, 0, stream>>>(k, XB, 1048576);
  k_proj<<<dim3(8, 64), 256, 0, stream>>>(XB, WkT, bk, KS, HK, KSTAB, 1);
  k_cast<<<4096, 256, 0, stream>>>(v, XB, 1048576);
  k_proj<<<dim3(8, 64), 256, 0, stream>>>(XB, WvT, bv, VH, HK, KSTAB, 2);
  k_chunksum<<<1024, 256, 0, stream>>>(KS, VH, RFt, HK, KSTAB, SS, ZS);
  k_prefix<<<256, 256, 0, stream>>>(SS, ZS, ZP);
  k_chunkout<<<1024, 256, 0, stream>>>(QS, KS, VH, SS, ZP, RFt, HK, KSTAB, CTX);
  k_proj<<<dim3(8, 64), 256, 0, stream>>>(CTX, WoT, bo, d_out, HK, KSTAB, 3);
  k_guard<<<32768, 256, 0, stream>>>((float*)d_out, ws_size, out_size);
  (void)in_sizes; (void)n_in;
}